// Round 11
// baseline (35.393 us; speedup 1.0000x reference)
//
#include <hip/hip_runtime.h>
#include <hip/hip_bf16.h>

// CRF loss: B=32, S=128, V=8, T=66.  256 chains; 2 waves per chain:
// wave0 = forward exp-domain recurrence (steps 1..63)  -> F = exp(alpha_63 - cF)
// wave1 = backward exp-domain recurrence (steps 127..64)-> G = exp(beta_63 - cG)
// Z = 2^(esumF+esumG) * sum_i F_i G_i.  Exact 2^-e rescaling; no div/exp/log
// on the critical path.  Main + extra(64/65) streams packed as float2 so the
// inner loop is v_pk_fma_f32 (2 FMA / instruction).
constexpr int TT = 66;
constexpr int SS = 128;
constexpr int NV = 8;

typedef float f32x2 __attribute__((ext_vector_type(2)));

__device__ __forceinline__ float rl(float v, int lane) {
    return __int_as_float(__builtin_amdgcn_readlane(__float_as_int(v), lane));
}

__global__ __launch_bounds__(128) void crf_chain_kernel(
    const float* __restrict__ score,        // [32,128,128,66]
    const float* __restrict__ trans,        // [66,66]
    const float* __restrict__ startt,       // [66]
    const float* __restrict__ endt,         // [66]
    const int*   __restrict__ v_label,      // [32,8]
    const int*   __restrict__ role_label,   // [32,8,128]
    float*       __restrict__ ws_nll)       // [256] per-chain nll
{
    __shared__ __align__(16) float xl[SS * TT];   // X = exp(emissions), 33792 B
    __shared__ float gbuf[TT + 2];                // G exchange + esumG
    const int tid  = threadIdx.x;
    const int lane = tid & 63;
    const int wid  = tid >> 6;
    const int bv   = blockIdx.x;
    const int b    = bv >> 3;
    const int v    = bv & 7;

    // ---- stage exp(emissions): 8448 floats = 2112 float4, 128 threads ----
    const int prow = v_label[b * NV + v];
    const float* src = score + ((size_t)(b * SS + prow) * (SS * TT));
    const float4* src4 = reinterpret_cast<const float4*>(src);
    float4* dst4 = reinterpret_cast<float4*>(xl);
    #pragma unroll
    for (int k = 0; k < 16; ++k) {                // 16*128 = 2048
        const int idx = k * 128 + tid;
        float4 tv = src4[idx];
        tv.x = __expf(tv.x); tv.y = __expf(tv.y);
        tv.z = __expf(tv.z); tv.w = __expf(tv.w);
        dst4[idx] = tv;
    }
    if (tid < 64) {                               // tail 64
        const int idx = 2048 + tid;
        float4 tv = src4[idx];
        tv.x = __expf(tv.x); tv.y = __expf(tv.y);
        tv.z = __expf(tv.z); tv.w = __expf(tv.w);
        dst4[idx] = tv;
    }

    // ---- gold score (wave 0 only; global reads, pre-barrier) ----
    const int* tags = role_label + bv * SS;
    float gold = 0.f;
    if (wid == 0) {
        const int s0 = lane;                      // 0..63
        const int tg0 = tags[s0];
        gold += src[s0 * TT + tg0];
        gold += trans[tg0 * TT + tags[s0 + 1]];
        const int s1 = lane + 64;                 // 64..127
        const int tg1 = tags[s1];
        gold += src[s1 * TT + tg1];
        if (lane < 63) gold += trans[tg1 * TT + tags[s1 + 1]];
        #pragma unroll
        for (int off = 32; off; off >>= 1) gold += __shfl_xor(gold, off);
        gold += startt[tags[0]] + endt[tags[SS - 1]];
    }

    // ---- per-wave packed weights: .x = own column/row, .y = col/row 64|65 ----
    // wave0 (forward): Wp[i].x = exp(trans[i][lane]), Wp[i].y = exp(trans[i][64|65])
    // wave1 (backward): Wp[j].x = exp(trans[lane][j]), Wp[j].y = exp(trans[64|65][j])
    const int xsel = (lane == 1) ? 65 : 64;
    f32x2 Wp[TT];
    if (wid == 0) {
        #pragma unroll
        for (int i = 0; i < TT; ++i) {
            Wp[i].x = __expf(trans[i * TT + lane]);
            Wp[i].y = __expf(trans[i * TT + xsel]);
        }
    } else {
        #pragma unroll
        for (int j = 0; j < TT; ++j) {
            Wp[j].x = __expf(trans[lane * TT + j]);
            Wp[j].y = __expf(trans[xsel * TT + j]);
        }
    }

    __syncthreads();

    int esum = 0;
    float F = 0.f, F64 = 0.f, F65 = 0.f;          // wave0 result
    if (wid == 0) {
        // ---- forward: F(0) = exp(start) * X_0; steps t = 1..63 ----
        F   = __expf(startt[lane]) * xl[lane];
        F64 = __expf(startt[64])   * xl[64];
        F65 = __expf(startt[65])   * xl[65];
        float xc   = xl[TT + lane];
        float xc64 = xl[TT + 64];
        float xc65 = xl[TT + 65];
        #pragma unroll 1
        for (int t = 1; t <= 63; ++t) {
            const int tn = (t < 63) ? t + 1 : t;
            const float xn   = xl[tn * TT + lane];
            const float xn64 = xl[tn * TT + 64];
            const float xn65 = xl[tn * TT + 65];

            f32x2 acc0 = Wp[64] * F64;
            f32x2 acc1 = Wp[65] * F65;
            f32x2 acc2 = (f32x2)(0.f);
            f32x2 acc3 = (f32x2)(0.f);
            #pragma unroll
            for (int i = 0; i < 64; i += 4) {
                const float a0 = rl(F, i + 0);
                const float a1 = rl(F, i + 1);
                const float a2 = rl(F, i + 2);
                const float a3 = rl(F, i + 3);
                acc0 += Wp[i + 0] * a0;           // v_pk_fma_f32
                acc1 += Wp[i + 1] * a1;
                acc2 += Wp[i + 2] * a2;
                acc3 += Wp[i + 3] * a3;
            }
            const float S  = (acc0.x + acc1.x) + (acc2.x + acc3.x);
            const float Sx = (acc0.y + acc1.y) + (acc2.y + acc3.y);
            const float S64 = rl(Sx, 0);
            const float S65 = rl(Sx, 1);

            const int sbits = __builtin_amdgcn_readfirstlane(__float_as_int(S));
            const int e = ((sbits >> 23) & 0xff) - 127;
            esum += e;
            const float r = __int_as_float((127 - e) << 23);   // 2^-e exact

            F   = (S   * r) * xc;
            F64 = (S64 * r) * xc64;
            F65 = (S65 * r) * xc65;
            xc = xn; xc64 = xn64; xc65 = xn65;
        }
    } else {
        // ---- backward: G(127) = exp(end); steps t = 127..64 ----
        float G   = __expf(endt[lane]);
        float G64 = __expf(endt[64]);
        float G65 = __expf(endt[65]);
        float xc   = xl[127 * TT + lane];
        float xc64 = xl[127 * TT + 64];
        float xc65 = xl[127 * TT + 65];
        #pragma unroll 1
        for (int t = 127; t >= 64; --t) {
            const int tn = (t > 64) ? t - 1 : t;
            const float xn   = xl[tn * TT + lane];
            const float xn64 = xl[tn * TT + 64];
            const float xn65 = xl[tn * TT + 65];

            const float Y   = G * xc;             // Y_j = X_t(j) * G_j
            const float Y64 = G64 * xc64;
            const float Y65 = G65 * xc65;

            f32x2 acc0 = Wp[64] * Y64;
            f32x2 acc1 = Wp[65] * Y65;
            f32x2 acc2 = (f32x2)(0.f);
            f32x2 acc3 = (f32x2)(0.f);
            #pragma unroll
            for (int j = 0; j < 64; j += 4) {
                const float y0 = rl(Y, j + 0);
                const float y1 = rl(Y, j + 1);
                const float y2 = rl(Y, j + 2);
                const float y3 = rl(Y, j + 3);
                acc0 += Wp[j + 0] * y0;           // v_pk_fma_f32
                acc1 += Wp[j + 1] * y1;
                acc2 += Wp[j + 2] * y2;
                acc3 += Wp[j + 3] * y3;
            }
            const float S  = (acc0.x + acc1.x) + (acc2.x + acc3.x);
            const float Sx = (acc0.y + acc1.y) + (acc2.y + acc3.y);
            const float S64 = rl(Sx, 0);
            const float S65 = rl(Sx, 1);

            const int sbits = __builtin_amdgcn_readfirstlane(__float_as_int(S));
            const int e = ((sbits >> 23) & 0xff) - 127;
            esum += e;
            const float r = __int_as_float((127 - e) << 23);

            G   = S   * r;
            G64 = S64 * r;
            G65 = S65 * r;
            xc = xn; xc64 = xn64; xc65 = xn65;
        }
        gbuf[lane] = G;
        if (lane == 0) {
            gbuf[64] = G64;
            gbuf[65] = G65;
            gbuf[66] = __int_as_float(esum);
        }
    }

    __syncthreads();

    if (wid == 0) {
        // ---- stitch: Z = 2^(esumF+esumG) * sum_i F_i * G_i ----
        float prod = F * gbuf[lane];
        #pragma unroll
        for (int off = 32; off; off >>= 1) prod += __shfl_xor(prod, off);
        const float tot = prod + F64 * gbuf[64] + F65 * gbuf[65];
        const int esumG = __float_as_int(gbuf[66]);
        const float log_z = (float)(esum + esumG) * 0.69314718056f + __logf(tot);
        if (lane == 0) ws_nll[bv] = log_z - gold;
    }
}

__global__ __launch_bounds__(64) void crf_reduce_kernel(
    const float* __restrict__ ws_nll, float* __restrict__ out)
{
    const int lane = threadIdx.x;
    float s = ws_nll[lane] + ws_nll[lane + 64] + ws_nll[lane + 128] + ws_nll[lane + 192];
    #pragma unroll
    for (int off = 32; off; off >>= 1) s += __shfl_xor(s, off);
    if (lane == 0) out[0] = s * (1.0f / 256.0f);
}

extern "C" void kernel_launch(void* const* d_in, const int* in_sizes, int n_in,
                              void* d_out, int out_size, void* d_ws, size_t ws_size,
                              hipStream_t stream) {
    const float* score  = (const float*)d_in[0];
    const float* trans  = (const float*)d_in[1];
    const float* startt = (const float*)d_in[2];
    const float* endt   = (const float*)d_in[3];
    const int*   v_label    = (const int*)d_in[4];
    const int*   role_label = (const int*)d_in[5];
    float* out = (float*)d_out;
    float* ws  = (float*)d_ws;

    crf_chain_kernel<<<256, 128, 0, stream>>>(score, trans, startt, endt,
                                              v_label, role_label, ws);
    crf_reduce_kernel<<<1, 64, 0, stream>>>(ws, out);
}